// Round 1
// baseline (202.154 us; speedup 1.0000x reference)
//
#include <hip/hip_runtime.h>
#include <climits>

// FirstSpikeDetector: out[b][t] = 1.0 iff t is the first index where
// spike_train[b][t] != 0, else 0.0. (Gate cascade NOT/AND/OR over a scan
// collapses to "keep only the first spike per row".)
//
// Layout: one 64-lane wave per row (T=2048). Read phase: float4 loads,
// 256 elements/wave/iter, early-exit via __ballot as soon as any lane sees a
// spike (expected after iter 0 at 10% firing rate -> ~1KB read per row).
// Write phase: 8 coalesced float4 store iterations of the one-hot row.

__global__ __launch_bounds__(256, 1) void first_spike_kernel(
    const float* __restrict__ in, float* __restrict__ out, int batch, int T) {
  const int lane = threadIdx.x & 63;
  const int wave = threadIdx.x >> 6;
  const int row  = blockIdx.x * 4 + wave;
  if (row >= batch) return;  // wave-uniform

  const float4* __restrict__ in4  = (const float4*)(in  + (size_t)row * T);
  float4*       __restrict__ out4 = (float4*)      (out + (size_t)row * T);
  const int iters = T >> 8;  // 64 lanes * 4 floats = 256 elems per iteration

  int first_idx = INT_MAX;
  for (int it = 0; it < iters; ++it) {
    float4 v = in4[(it << 6) + lane];
    const int base = (it << 8) + (lane << 2);
    int local = INT_MAX;
    // priority order: lowest index wins within the lane
    if (v.w != 0.0f) local = base + 3;
    if (v.z != 0.0f) local = base + 2;
    if (v.y != 0.0f) local = base + 1;
    if (v.x != 0.0f) local = base + 0;
    if (__ballot(local != INT_MAX)) {  // wave-uniform: any spike in this chunk?
      int m = local;
#pragma unroll
      for (int off = 1; off < 64; off <<= 1)
        m = min(m, __shfl_xor(m, off, 64));
      first_idx = m;  // global first index for this row (chunks scanned in order)
      break;
    }
  }

#pragma unroll
  for (int it = 0; it < iters; ++it) {
    const int base = (it << 8) + (lane << 2);
    float4 o;
    o.x = (base + 0 == first_idx) ? 1.0f : 0.0f;
    o.y = (base + 1 == first_idx) ? 1.0f : 0.0f;
    o.z = (base + 2 == first_idx) ? 1.0f : 0.0f;
    o.w = (base + 3 == first_idx) ? 1.0f : 0.0f;
    out4[(it << 6) + lane] = o;
  }
}

extern "C" void kernel_launch(void* const* d_in, const int* in_sizes, int n_in,
                              void* d_out, int out_size, void* d_ws, size_t ws_size,
                              hipStream_t stream) {
  const float* in = (const float*)d_in[0];
  float* out = (float*)d_out;
  const int T = 2048;                 // time axis per reference setup_inputs
  const int batch = in_sizes[0] / T;  // 16384
  const int waves_per_block = 4;      // 256 threads = 4 wave64, one row each
  dim3 grid((batch + waves_per_block - 1) / waves_per_block);
  first_spike_kernel<<<grid, 256, 0, stream>>>(in, out, batch, T);
}